// Round 1
// 452.218 us; speedup vs baseline: 1.0667x; 1.0667x over previous
//
#include <hip/hip_runtime.h>
#include <math.h>

#define HIDDEN 1024
#define HEADS 8
#define HEAD 128
#define BATCH 512
#define RSQRT_D 0.08838834764831845f   // 1/sqrt(128)

typedef float f4 __attribute__((ext_vector_type(4)));

__device__ __forceinline__ float dot4(f4 a, f4 b) {
    return a.x * b.x + a.y * b.y + a.z * b.z + a.w * b.w;
}

// ---------------------------------------------------------------------------
// Single fused kernel: one block per (b,h).
//  Phase 1: gate pre-activation for THIS head only:
//           igp/fgp = concat(q,k,v)[b] . W[h] + b[h]  (9 float4 loads/thread,
//           W rows are L2-resident), then log-sigmoid / max-state update.
//  Phase 2: stream the 128x128 cell tile once with NONTEMPORAL load/store
//           (read-once/write-once 512 MiB stream — don't allocate in L2/L3):
//           cell_new = f*c + (i*k_hat[d1])*v[d2]; numerator = q . cell_new.
//  Phase 3: norm_new, denominator, GroupNorm epilogue in wave 0, lanes 0-31,
//           with shfl broadcasts (no extra barriers).
// ---------------------------------------------------------------------------
__global__ __launch_bounds__(256) void mlstm_fused(
    const float* __restrict__ q, const float* __restrict__ k,
    const float* __restrict__ v,
    const float* __restrict__ cell_state, const float* __restrict__ norm_state,
    const float* __restrict__ max_state,
    const float* __restrict__ Wi, const float* __restrict__ bi,
    const float* __restrict__ Wf, const float* __restrict__ bf,
    const float* __restrict__ gn_gamma, const float* __restrict__ gn_beta,
    float* __restrict__ out, float* __restrict__ cell_new,
    float* __restrict__ norm_new, float* __restrict__ maxnew_out)
{
    const int bh = blockIdx.x;
    const int b = bh >> 3, h = bh & 7;
    const int t = threadIdx.x;
    const int tx = t & 31, ty = t >> 5;

    __shared__ __align__(16) float q_s[HEAD];
    __shared__ __align__(16) float kh_s[HEAD];
    __shared__ f4 red[8][32];
    __shared__ float part_i[4], part_f[4];
    __shared__ float gate_s[3];   // i_gate, f_gate, exp(-max_new)

    const float* qrow = q + b * HIDDEN + h * HEAD;
    const float* krow = k + b * HIDDEN + h * HEAD;
    const float* vrow = v + b * HIDDEN + h * HEAD;

    // ---- stage q and k_hat for this head ----
    if (t < HEAD) {
        q_s[t]  = qrow[t];
        kh_s[t] = krow[t] * RSQRT_D;
    }

    // ---- phase 1: gate dot for THIS head only ----
    {
        const f4* qf = (const f4*)(q + b * HIDDEN);
        const f4* kf = (const f4*)(k + b * HIDDEN);
        const f4* vf = (const f4*)(v + b * HIDDEN);
        const f4* wi = (const f4*)(Wi + h * 3 * HIDDEN);
        const f4* wf = (const f4*)(Wf + h * 3 * HIDDEN);

        // HIDDEN/4 == 256 == blockDim.x: each thread owns exactly one f4 slot
        const f4 xq = qf[t], xk = kf[t], xv = vf[t];
        const f4 wiq = wi[t], wik = wi[256 + t], wiv = wi[512 + t];
        const f4 wfq = wf[t], wfk = wf[256 + t], wfv = wf[512 + t];

        float acc_i = dot4(xq, wiq) + dot4(xk, wik) + dot4(xv, wiv);
        float acc_f = dot4(xq, wfq) + dot4(xk, wfk) + dot4(xv, wfv);

        #pragma unroll
        for (int off = 32; off > 0; off >>= 1) {
            acc_i += __shfl_down(acc_i, off, 64);
            acc_f += __shfl_down(acc_f, off, 64);
        }
        if ((t & 63) == 0) {
            part_i[t >> 6] = acc_i;
            part_f[t >> 6] = acc_f;
        }
    }
    __syncthreads();

    if (t == 0) {
        float igp = part_i[0] + part_i[1] + part_i[2] + part_i[3] + bi[h];
        float fgp = part_f[0] + part_f[1] + part_f[2] + part_f[3] + bf[h];
        // stable log_sigmoid
        float lf = (fgp >= 0.f) ? -log1pf(expf(-fgp)) : (fgp - log1pf(expf(fgp)));
        float m_old = max_state[bh];
        float m_new = fmaxf(igp, m_old + lf);
        gate_s[0] = expf(igp - m_new);
        gate_s[1] = expf(lf + m_old - m_new);
        gate_s[2] = expf(-m_new);
        maxnew_out[bh] = m_new;
    }
    __syncthreads();

    const float i_gate = gate_s[0];
    const float f_gate = gate_s[1];

    // ---- phase 2: stream the cell tile (nontemporal both directions) ----
    const f4* c_in  = (const f4*)(cell_state + (size_t)bh * HEAD * HEAD);
    f4*       c_out = (f4*)(cell_new + (size_t)bh * HEAD * HEAD);
    const f4 v4 = ((const f4*)vrow)[tx];

    f4 num = {0.f, 0.f, 0.f, 0.f};
    #pragma unroll
    for (int i = 0; i < 16; ++i) {
        const int d1 = ty + (i << 3);
        f4 c = __builtin_nontemporal_load(c_in + d1 * 32 + tx);
        const float a = i_gate * kh_s[d1];
        f4 nc = f_gate * c + a * v4;
        __builtin_nontemporal_store(nc, c_out + d1 * 32 + tx);
        num += q_s[d1] * nc;
    }
    red[ty][tx] = num;
    __syncthreads();

    // ---- phase 3: reduce + norm_new + denominator + GroupNorm (wave 0) ----
    if (ty == 0) {
        f4 s = red[0][tx];
        #pragma unroll
        for (int r = 1; r < 8; ++r) s += red[r][tx];

        const f4 ns  = ((const f4*)(norm_state + (size_t)bh * HEAD))[tx];
        const f4 q4  = ((const f4*)q_s)[tx];
        const f4 kh4 = ((const f4*)kh_s)[tx];
        f4 nn = f_gate * ns + i_gate * kh4;
        ((f4*)(norm_new + (size_t)bh * HEAD))[tx] = nn;

        float qn = dot4(q4, nn);
        #pragma unroll
        for (int off = 16; off > 0; off >>= 1)
            qn += __shfl_down(qn, off, 32);
        qn = __shfl(qn, 0, 32);

        const float inv_d = 1.0f / (fmaxf(fabsf(qn), gate_s[2]) + 1e-6f);

        f4 o = s * inv_d;
        float sm = o.x + o.y + o.z + o.w;
        float ss = o.x * o.x + o.y * o.y + o.z * o.z + o.w * o.w;
        #pragma unroll
        for (int off = 16; off > 0; off >>= 1) {
            sm += __shfl_down(sm, off, 32);
            ss += __shfl_down(ss, off, 32);
        }
        sm = __shfl(sm, 0, 32);
        ss = __shfl(ss, 0, 32);

        const float mean = sm * (1.f / 128.f);
        const float var  = ss * (1.f / 128.f) - mean * mean;
        const float rstd = rsqrtf(var + 1e-5f);

        const f4 g4 = ((const f4*)(gn_gamma + h * HEAD))[tx];
        const f4 b4 = ((const f4*)(gn_beta  + h * HEAD))[tx];
        f4 res;
        res.x = fmaf((o.x - mean) * rstd, g4.x, b4.x);
        res.y = fmaf((o.y - mean) * rstd, g4.y, b4.y);
        res.z = fmaf((o.z - mean) * rstd, g4.z, b4.z);
        res.w = fmaf((o.w - mean) * rstd, g4.w, b4.w);
        ((f4*)(out + (size_t)bh * HEAD))[tx] = res;
    }
}

// ---------------------------------------------------------------------------
extern "C" void kernel_launch(void* const* d_in, const int* in_sizes, int n_in,
                              void* d_out, int out_size, void* d_ws, size_t ws_size,
                              hipStream_t stream)
{
    const float* q          = (const float*)d_in[0];
    const float* k          = (const float*)d_in[1];
    const float* v          = (const float*)d_in[2];
    const float* cell_state = (const float*)d_in[3];
    const float* norm_state = (const float*)d_in[4];
    const float* max_state  = (const float*)d_in[5];
    const float* Wi         = (const float*)d_in[6];
    const float* bi         = (const float*)d_in[7];
    const float* Wf         = (const float*)d_in[8];
    const float* bf         = (const float*)d_in[9];
    const float* gn_gamma   = (const float*)d_in[10];
    const float* gn_beta    = (const float*)d_in[11];

    // outputs concatenated flat in return order: out, cell_new, norm_new, max_new
    float* out      = (float*)d_out;
    float* cell_new = out      + (size_t)BATCH * HIDDEN;
    float* norm_new = cell_new + (size_t)BATCH * HEADS * HEAD * HEAD;
    float* max_new  = norm_new + (size_t)BATCH * HEADS * HEAD;

    mlstm_fused<<<BATCH * HEADS, 256, 0, stream>>>(
        q, k, v, cell_state, norm_state, max_state,
        Wi, bi, Wf, bf, gn_gamma, gn_beta,
        out, cell_new, norm_new, max_new);
}